// Round 1
// baseline (1738.787 us; speedup 1.0000x reference)
//
#include <hip/hip_runtime.h>
#include <math.h>

#define CCH 512
#define NH 4
#define HD 128
#define HW 1024
#define BATCH 16
#define NGRP 32
#define CPG 16
#define EPS 1e-5f

// ---------------- GroupNorm: one block per (batch, group) ----------------
__global__ __launch_bounds__(256) void gn_kernel(const float* __restrict__ x,
                                                 const float* __restrict__ gamma,
                                                 const float* __restrict__ beta,
                                                 float* __restrict__ hn) {
  int bg = blockIdx.x;
  int b = bg >> 5, g = bg & 31;
  const float* xp = x + ((size_t)b * CCH + (size_t)g * CPG) * HW;
  float* op = hn + ((size_t)b * CCH + (size_t)g * CPG) * HW;
  int t = threadIdx.x;
  float s = 0.f, ss = 0.f;
  for (int i = t; i < CPG * HW; i += 256) {
    float v = xp[i];
    s += v;
    ss += v * v;
  }
#pragma unroll
  for (int off = 32; off > 0; off >>= 1) {
    s += __shfl_xor(s, off, 64);
    ss += __shfl_xor(ss, off, 64);
  }
  __shared__ float rs[4], rss[4];
  int w = t >> 6;
  if ((t & 63) == 0) { rs[w] = s; rss[w] = ss; }
  __syncthreads();
  s = rs[0] + rs[1] + rs[2] + rs[3];
  ss = rss[0] + rss[1] + rss[2] + rss[3];
  const float invn = 1.f / (CPG * HW);
  float mean = s * invn;
  float var = ss * invn - mean * mean;
  float rstd = rsqrtf(var + EPS);
  for (int i = t; i < CPG * HW; i += 256) {
    int ch = g * CPG + (i >> 10);
    float v = (xp[i] - mean) * rstd;
    op[i] = v * gamma[ch] + beta[ch];
  }
}

// ---- fp32 GEMM: out[b][m][n] = sum_k W[m][k] * X[b][k][n] + bias[m] (+resid)
// M=512, N=1024 (HW), K=512. Tiles 64x64x16, 256 threads, 4x4 per thread.
__global__ __launch_bounds__(256) void gemm_kernel(const float* __restrict__ W,
                                                   const float* __restrict__ X,
                                                   const float* __restrict__ bias,
                                                   const float* __restrict__ resid,
                                                   float* __restrict__ out) {
  int b = blockIdx.z;
  int m0 = blockIdx.y * 64, n0 = blockIdx.x * 64;
  const float* Xb = X + (size_t)b * CCH * HW;
  float* Ob = out + (size_t)b * CCH * HW;
  __shared__ float As[16][68];  // [k][m], pad 68 -> 16B-aligned float4 rows
  __shared__ float Bs[16][68];  // [k][n]
  int t = threadIdx.x;
  int tx = t & 15, ty = t >> 4;
  float acc[4][4] = {};
  for (int k0 = 0; k0 < CCH; k0 += 16) {
#pragma unroll
    for (int i = 0; i < 4; ++i) {
      int ee = i * 256 + t;
      int m = ee >> 4, k = ee & 15;
      As[k][m] = W[(size_t)(m0 + m) * CCH + k0 + k];
    }
#pragma unroll
    for (int i = 0; i < 4; ++i) {
      int ee = i * 256 + t;
      int k = ee >> 6, n = ee & 63;
      Bs[k][n] = Xb[(size_t)(k0 + k) * HW + n0 + n];
    }
    __syncthreads();
#pragma unroll
    for (int kk = 0; kk < 16; ++kk) {
      float4 a = *(const float4*)&As[kk][ty * 4];
      float4 bv = *(const float4*)&Bs[kk][tx * 4];
      float av[4] = {a.x, a.y, a.z, a.w};
      float bb[4] = {bv.x, bv.y, bv.z, bv.w};
#pragma unroll
      for (int i = 0; i < 4; ++i)
#pragma unroll
        for (int j = 0; j < 4; ++j) acc[i][j] += av[i] * bb[j];
    }
    __syncthreads();
  }
#pragma unroll
  for (int i = 0; i < 4; ++i) {
    int m = m0 + ty * 4 + i;
    float bia = bias[m];
    float4 v = make_float4(acc[i][0] + bia, acc[i][1] + bia, acc[i][2] + bia,
                           acc[i][3] + bia);
    size_t off = (size_t)b * CCH * HW + (size_t)m * HW + n0 + tx * 4;
    if (resid) {
      float4 rv = *(const float4*)&resid[off];
      v.x += rv.x; v.y += rv.y; v.z += rv.z; v.w += rv.w;
    }
    *(float4*)&Ob[(size_t)m * HW + n0 + tx * 4] = v;
  }
}

// ---------------- Attention: one block per (batch, head, 8-query tile) ----
// Q,K,V layout [B][C][HW], head h = channels h*HD .. h*HD+127.
__global__ __launch_bounds__(256) void attn_kernel(const float* __restrict__ Q,
                                                   const float* __restrict__ K,
                                                   const float* __restrict__ V,
                                                   float* __restrict__ O) {
  int b = blockIdx.z, h = blockIdx.y;
  int q0 = blockIdx.x * 8;
  size_t base = ((size_t)b * CCH + (size_t)h * HD) * HW;
  __shared__ float Qs[8][HD];     // 4 KB
  __shared__ float S[8][HW];      // 32 KB
  __shared__ float Vt[HD][34];    // 17 KB, pad 34 -> lane stride 2 (free)
  __shared__ float lsum[8];
  int t = threadIdx.x;
  // Load 8 q-columns (8x128)
#pragma unroll
  for (int i = 0; i < 4; ++i) {
    int e = i * 256 + t;
    int d = e >> 3, qi = e & 7;
    Qs[qi][d] = Q[base + (size_t)d * HW + q0 + qi];
  }
  __syncthreads();
  // Scores: thread t owns keys 4t..4t+3 for all 8 queries
  float acc[8][4] = {};
  const float4* Kp = (const float4*)(K + base);
#pragma unroll 4
  for (int d = 0; d < HD; ++d) {
    float4 kv = Kp[(size_t)d * 256 + t];
#pragma unroll
    for (int qi = 0; qi < 8; ++qi) {
      float qd = Qs[qi][d];
      acc[qi][0] += qd * kv.x;
      acc[qi][1] += qd * kv.y;
      acc[qi][2] += qd * kv.z;
      acc[qi][3] += qd * kv.w;
    }
  }
  const float scale = 0.08838834764831845f;  // 1/sqrt(128)
#pragma unroll
  for (int qi = 0; qi < 8; ++qi) {
    float4 v = make_float4(acc[qi][0] * scale, acc[qi][1] * scale,
                           acc[qi][2] * scale, acc[qi][3] * scale);
    *(float4*)&S[qi][t * 4] = v;
  }
  __syncthreads();
  // Exact softmax per row: 32 threads per query row
  {
    int qi = t >> 5, l = t & 31;
    float m = -1e30f;
#pragma unroll 8
    for (int i = 0; i < 32; ++i) m = fmaxf(m, S[qi][l + 32 * i]);
#pragma unroll
    for (int off = 16; off > 0; off >>= 1) m = fmaxf(m, __shfl_xor(m, off, 32));
    float sum = 0.f;
#pragma unroll 8
    for (int i = 0; i < 32; ++i) {
      float p = __expf(S[qi][l + 32 * i] - m);
      S[qi][l + 32 * i] = p;
      sum += p;
    }
#pragma unroll
    for (int off = 16; off > 0; off >>= 1) sum += __shfl_xor(sum, off, 32);
    if (l == 0) lsum[qi] = sum;
  }
  // PV: thread (qi = t>>5, l = t&31) owns d = l, l+32, l+64, l+96
  int qi = t >> 5, l = t & 31;
  float o[4] = {};
  for (int kt = 0; kt < 32; ++kt) {
    __syncthreads();  // protect Vt (also covers softmax->PV hazard at kt=0)
#pragma unroll
    for (int r = 0; r < 4; ++r) {
      int e = r * 256 + t;
      int d = e >> 3, j4 = e & 7;
      float4 v = *(const float4*)&V[base + (size_t)d * HW + kt * 32 + j4 * 4];
      Vt[d][j4 * 4 + 0] = v.x;
      Vt[d][j4 * 4 + 1] = v.y;
      Vt[d][j4 * 4 + 2] = v.z;
      Vt[d][j4 * 4 + 3] = v.w;
    }
    __syncthreads();
    const float* Sp = &S[qi][kt * 32];
#pragma unroll
    for (int j = 0; j < 32; j += 2) {
      float2 p = *(const float2*)&Sp[j];
#pragma unroll
      for (int mi = 0; mi < 4; ++mi) {
        float2 v = *(const float2*)&Vt[l + 32 * mi][j];
        o[mi] += p.x * v.x + p.y * v.y;
      }
    }
  }
  float inv = 1.f / lsum[qi];
#pragma unroll
  for (int mi = 0; mi < 4; ++mi)
    O[base + (size_t)(l + 32 * mi) * HW + q0 + qi] = o[mi] * inv;
}

extern "C" void kernel_launch(void* const* d_in, const int* in_sizes, int n_in,
                              void* d_out, int out_size, void* d_ws,
                              size_t ws_size, hipStream_t stream) {
  const float* x = (const float*)d_in[0];
  const float* gamma = (const float*)d_in[1];
  const float* beta = (const float*)d_in[2];
  const float* wq = (const float*)d_in[3];
  const float* bq = (const float*)d_in[4];
  const float* wk = (const float*)d_in[5];
  const float* bk = (const float*)d_in[6];
  const float* wv = (const float*)d_in[7];
  const float* bv = (const float*)d_in[8];
  const float* wp = (const float*)d_in[9];
  const float* bp = (const float*)d_in[10];
  float* out = (float*)d_out;
  float* ws = (float*)d_ws;

  const size_t T = (size_t)BATCH * CCH * HW;  // 8M floats per tensor
  float* hn = ws;
  float* Qb = ws + T;
  float* Kb = ws + 2 * T;
  float* Vb = ws + 3 * T;
  float* Ob = hn;  // hn no longer needed once QKV GEMMs are done

  gn_kernel<<<dim3(BATCH * NGRP), 256, 0, stream>>>(x, gamma, beta, hn);
  dim3 gg(HW / 64, CCH / 64, BATCH);
  gemm_kernel<<<gg, 256, 0, stream>>>(wq, hn, bq, nullptr, Qb);
  gemm_kernel<<<gg, 256, 0, stream>>>(wk, hn, bk, nullptr, Kb);
  gemm_kernel<<<gg, 256, 0, stream>>>(wv, hn, bv, nullptr, Vb);
  attn_kernel<<<dim3(HW / 8, NH, BATCH), 256, 0, stream>>>(Qb, Kb, Vb, Ob);
  gemm_kernel<<<gg, 256, 0, stream>>>(wp, Ob, bp, x, out);
}

// Round 2
// 265.281 us; speedup vs baseline: 6.5545x; 6.5545x over previous
//
#include <hip/hip_runtime.h>
#include <math.h>

#define CCH 512
#define NH 4
#define HD 128
#define HW 1024
#define BATCH 16
#define EPS 1e-5f

typedef __attribute__((ext_vector_type(8))) short bfrag;   // 8 bf16 = 4 VGPRs
typedef __attribute__((ext_vector_type(4))) float f4;

static __device__ __forceinline__ unsigned short f2bf(float f) {
  union { float f; unsigned u; } v;
  v.f = f;
  unsigned r = v.u + 0x7fff + ((v.u >> 16) & 1);  // RNE
  return (unsigned short)(r >> 16);
}
static __device__ __forceinline__ unsigned pack2(unsigned short a, unsigned short b) {
  return (unsigned)a | ((unsigned)b << 16);
}

// ---------- weights fp32 -> bf16 (4 matrices, blockIdx.y selects) ----------
__global__ __launch_bounds__(256) void wcvt_kernel(const float* __restrict__ s0,
                                                   const float* __restrict__ s1,
                                                   const float* __restrict__ s2,
                                                   const float* __restrict__ s3,
                                                   unsigned short* __restrict__ d) {
  const float* srcs[4] = {s0, s1, s2, s3};
  const float* s = srcs[blockIdx.y];
  unsigned short* dp = d + (size_t)blockIdx.y * CCH * CCH;
  int i = blockIdx.x * 256 + threadIdx.x;  // 65536 float4 per matrix
  f4 v = ((const f4*)s)[i];
  ushort4 o;
  o.x = f2bf(v.x); o.y = f2bf(v.y); o.z = f2bf(v.z); o.w = f2bf(v.w);
  ((ushort4*)dp)[i] = o;
}

// ---------- GroupNorm -> position-major bf16 hn_t[b][hw][c] ----------
__global__ __launch_bounds__(256) void gn_kernel(const float* __restrict__ x,
                                                 const float* __restrict__ gamma,
                                                 const float* __restrict__ beta,
                                                 unsigned short* __restrict__ hn) {
  int b = blockIdx.x >> 5, g = blockIdx.x & 31;
  const float* xp = x + ((size_t)b * CCH + g * 16) * HW;  // 16 ch x 1024
  int t = threadIdx.x;
  float s = 0.f, ss = 0.f;
  const f4* xp4 = (const f4*)xp;
  for (int i = t; i < 4096; i += 256) {
    f4 v = xp4[i];
    s += v.x + v.y + v.z + v.w;
    ss += v.x * v.x + v.y * v.y + v.z * v.z + v.w * v.w;
  }
#pragma unroll
  for (int off = 32; off > 0; off >>= 1) {
    s += __shfl_xor(s, off);
    ss += __shfl_xor(ss, off);
  }
  __shared__ float rs[4], rss[4];
  int w = t >> 6;
  if ((t & 63) == 0) { rs[w] = s; rss[w] = ss; }
  __syncthreads();
  s = rs[0] + rs[1] + rs[2] + rs[3];
  ss = rss[0] + rss[1] + rss[2] + rss[3];
  const float invn = 1.f / (16 * HW);
  float mean = s * invn;
  float var = ss * invn - mean * mean;
  float rstd = rsqrtf(var + EPS);
  float a_[16], b_[16];
#pragma unroll
  for (int c = 0; c < 16; ++c) {
    float gm = gamma[g * 16 + c] * rstd;
    a_[c] = gm;
    b_[c] = beta[g * 16 + c] - mean * gm;
  }
#pragma unroll
  for (int i = 0; i < 4; ++i) {
    int p = t + 256 * i;
    unsigned short tv[16];
#pragma unroll
    for (int c = 0; c < 16; ++c) tv[c] = f2bf(xp[c * HW + p] * a_[c] + b_[c]);
    uint4 u0, u1;
    u0.x = pack2(tv[0], tv[1]);  u0.y = pack2(tv[2], tv[3]);
    u0.z = pack2(tv[4], tv[5]);  u0.w = pack2(tv[6], tv[7]);
    u1.x = pack2(tv[8], tv[9]);  u1.y = pack2(tv[10], tv[11]);
    u1.z = pack2(tv[12], tv[13]); u1.w = pack2(tv[14], tv[15]);
    unsigned short* dst = hn + ((size_t)b * HW + p) * CCH + g * 16;
    *(uint4*)dst = u0;
    *(uint4*)(dst + 8) = u1;
  }
}

// ---------- MFMA GEMM: D[pos][ch] = sum_k Xt[pos][k] * W[ch][k] + bias ----
// MODE 0: bf16 out position-major [b][pos][ch]   (Q, K)
// MODE 1: bf16 out channel-major  [b][ch][pos]   (V)
// MODE 2: fp32 out channel-major + residual      (proj -> d_out)
template <int MODE>
__global__ __launch_bounds__(256, 2) void gemm_kernel(
    const unsigned short* __restrict__ Xt, const unsigned short* __restrict__ Wb,
    const float* __restrict__ bias, const float* __restrict__ resid,
    void* __restrict__ outp) {
  int b = blockIdx.z;
  int p0 = blockIdx.y * 128;  // position tile
  int c0 = blockIdx.x * 128;  // out-channel tile
  __shared__ __align__(16) unsigned short Xs[128][40];  // rows 80B = 5x16B
  __shared__ __align__(16) unsigned short Ws[128][40];
  int t = threadIdx.x;
  int w = t >> 6, lane = t & 63, l15 = lane & 15, quad = lane >> 4;
  int wp = (w & 1) * 64, wc = (w >> 1) * 64;
  const unsigned short* Xb = Xt + (size_t)b * HW * CCH;
  f4 acc[4][4] = {};  // [pt][ct]
  for (int k0 = 0; k0 < CCH; k0 += 32) {
    __syncthreads();
#pragma unroll
    for (int i = 0; i < 2; ++i) {
      int slot = t + 256 * i;
      int r = slot >> 2, cc = slot & 3;
      *(uint4*)&Xs[r][cc * 8] =
          *(const uint4*)&Xb[(size_t)(p0 + r) * CCH + k0 + cc * 8];
      *(uint4*)&Ws[r][cc * 8] =
          *(const uint4*)&Wb[(size_t)(c0 + r) * CCH + k0 + cc * 8];
    }
    __syncthreads();
    bfrag af[4], bf[4];
#pragma unroll
    for (int pt = 0; pt < 4; ++pt)
      af[pt] = *(const bfrag*)&Xs[wp + pt * 16 + l15][quad * 8];
#pragma unroll
    for (int ct = 0; ct < 4; ++ct)
      bf[ct] = *(const bfrag*)&Ws[wc + ct * 16 + l15][quad * 8];
#pragma unroll
    for (int pt = 0; pt < 4; ++pt)
#pragma unroll
      for (int ct = 0; ct < 4; ++ct)
        acc[pt][ct] = __builtin_amdgcn_mfma_f32_16x16x32_bf16(
            af[pt], bf[ct], acc[pt][ct], 0, 0, 0);
  }
  // epilogue
#pragma unroll
  for (int ct = 0; ct < 4; ++ct) {
    int ch = c0 + wc + ct * 16 + l15;
    float bi = bias[ch];
#pragma unroll
    for (int pt = 0; pt < 4; ++pt) {
      int pos = p0 + wp + pt * 16 + quad * 4;
      f4 v = acc[pt][ct];
      if (MODE == 0) {
        unsigned short* O = (unsigned short*)outp + (size_t)b * HW * CCH;
        O[(size_t)(pos + 0) * CCH + ch] = f2bf(v.x + bi);
        O[(size_t)(pos + 1) * CCH + ch] = f2bf(v.y + bi);
        O[(size_t)(pos + 2) * CCH + ch] = f2bf(v.z + bi);
        O[(size_t)(pos + 3) * CCH + ch] = f2bf(v.w + bi);
      } else if (MODE == 1) {
        unsigned short* O = (unsigned short*)outp + (size_t)b * CCH * HW;
        ushort4 st;
        st.x = f2bf(v.x + bi); st.y = f2bf(v.y + bi);
        st.z = f2bf(v.z + bi); st.w = f2bf(v.w + bi);
        *(ushort4*)&O[(size_t)ch * HW + pos] = st;
      } else {
        float* O = (float*)outp + (size_t)b * CCH * HW;
        const float* R = resid + (size_t)b * CCH * HW + (size_t)ch * HW + pos;
        float4 rv = *(const float4*)R;
        float4 st;
        st.x = v.x + bi + rv.x; st.y = v.y + bi + rv.y;
        st.z = v.z + bi + rv.z; st.w = v.w + bi + rv.w;
        *(float4*)&O[(size_t)ch * HW + pos] = st;
      }
    }
  }
}

// ---------- Flash attention: q-tile 128/block, kk-tiles of 64 ----------
// Qt,Kt position-major [b][hw][c]; Vc channel-major [b][c][hw]; Ot pos-major.
__global__ __launch_bounds__(256, 2) void attn_kernel(
    const unsigned short* __restrict__ Qt, const unsigned short* __restrict__ Kt,
    const unsigned short* __restrict__ Vc, unsigned short* __restrict__ Ot) {
  int b = blockIdx.z, h = blockIdx.y, q0 = blockIdx.x * 128;
  int t = threadIdx.x;
  int w = t >> 6, lane = t & 63, l15 = lane & 15, quad = lane >> 4;
  __shared__ __align__(16) unsigned short Ks[64][136];  // rows 272B = 17x16B
  __shared__ __align__(16) unsigned short Vs[128][72];  // rows 144B = 9x16B
  __shared__ __align__(16) unsigned short Ps[128][72];
  // Q fragments (loop-invariant): q = q0 + w*32 + qs*16 + l15
  bfrag qf[2][4];
#pragma unroll
  for (int qs = 0; qs < 2; ++qs)
#pragma unroll
    for (int ks = 0; ks < 4; ++ks)
      qf[qs][ks] = *(const bfrag*)&Qt[((size_t)b * HW + q0 + w * 32 + qs * 16 + l15) * CCH +
                                      h * HD + ks * 32 + quad * 8];
  f4 o[2][8] = {};  // [qs][dt], D[m=d][n=q]
  float mrow[2] = {-1e30f, -1e30f}, lrow[2] = {0.f, 0.f};
  const float scale = 0.08838834764831845f;  // 1/sqrt(128)
  for (int kt = 0; kt < 16; ++kt) {
    int kk0 = kt * 64;
    __syncthreads();  // staging buffers free, prev Ps consumed
#pragma unroll
    for (int i = 0; i < 4; ++i) {  // Ks: 64 rows x 128 bf16
      int slot = t + 256 * i;
      int r = slot >> 4, c = slot & 15;
      *(uint4*)&Ks[r][c * 8] =
          *(const uint4*)&Kt[((size_t)b * HW + kk0 + r) * CCH + h * HD + c * 8];
    }
#pragma unroll
    for (int i = 0; i < 4; ++i) {  // Vs: 128 rows x 64 bf16
      int slot = t + 256 * i;
      int r = slot >> 3, c = slot & 7;
      *(uint4*)&Vs[r][c * 8] =
          *(const uint4*)&Vc[((size_t)b * CCH + h * HD + r) * HW + kk0 + c * 8];
    }
    __syncthreads();
    // QK^T: D[m=kk][n=q]; A = K rows from LDS, B = Q frags from regs
    f4 S[2][4] = {};
#pragma unroll
    for (int ks = 0; ks < 4; ++ks) {
      bfrag kf[4];
#pragma unroll
      for (int mt = 0; mt < 4; ++mt)
        kf[mt] = *(const bfrag*)&Ks[mt * 16 + l15][ks * 32 + quad * 8];
#pragma unroll
      for (int qs = 0; qs < 2; ++qs)
#pragma unroll
        for (int mt = 0; mt < 4; ++mt)
          S[qs][mt] = __builtin_amdgcn_mfma_f32_16x16x32_bf16(
              kf[mt], qf[qs][ks], S[qs][mt], 0, 0, 0);
    }
    // online softmax in regs; lane's q = q0 + w*32 + qs*16 + l15
#pragma unroll
    for (int qs = 0; qs < 2; ++qs) {
      float vv[16];
#pragma unroll
      for (int mt = 0; mt < 4; ++mt)
#pragma unroll
        for (int r = 0; r < 4; ++r) vv[mt * 4 + r] = S[qs][mt][r] * scale;
      float tm = vv[0];
#pragma unroll
      for (int i = 1; i < 16; ++i) tm = fmaxf(tm, vv[i]);
      tm = fmaxf(tm, __shfl_xor(tm, 16));
      tm = fmaxf(tm, __shfl_xor(tm, 32));
      float mnew = fmaxf(mrow[qs], tm);
      float alpha = __expf(mrow[qs] - mnew);
      float sum = 0.f;
      unsigned short pk[16];
#pragma unroll
      for (int i = 0; i < 16; ++i) {
        float p = __expf(vv[i] - mnew);
        sum += p;
        pk[i] = f2bf(p);
      }
      sum += __shfl_xor(sum, 16);
      sum += __shfl_xor(sum, 32);
      lrow[qs] = lrow[qs] * alpha + sum;
      mrow[qs] = mnew;
#pragma unroll
      for (int dt = 0; dt < 8; ++dt) o[qs][dt] *= alpha;
#pragma unroll
      for (int mt = 0; mt < 4; ++mt) {
        ushort4 st;
        st.x = pk[mt * 4 + 0]; st.y = pk[mt * 4 + 1];
        st.z = pk[mt * 4 + 2]; st.w = pk[mt * 4 + 3];
        *(ushort4*)&Ps[w * 32 + qs * 16 + l15][mt * 16 + quad * 4] = st;
      }
    }
    __syncthreads();
    // PV: D[m=d][n=q]; A = V rows from LDS, B = P rows from LDS
#pragma unroll
    for (int ks = 0; ks < 2; ++ks) {
      bfrag pf[2];
#pragma unroll
      for (int qs = 0; qs < 2; ++qs)
        pf[qs] = *(const bfrag*)&Ps[w * 32 + qs * 16 + l15][ks * 32 + quad * 8];
#pragma unroll
      for (int dt = 0; dt < 8; ++dt) {
        bfrag vf = *(const bfrag*)&Vs[dt * 16 + l15][ks * 32 + quad * 8];
#pragma unroll
        for (int qs = 0; qs < 2; ++qs)
          o[qs][dt] = __builtin_amdgcn_mfma_f32_16x16x32_bf16(
              vf, pf[qs], o[qs][dt], 0, 0, 0);
      }
    }
  }
  // epilogue: O /= l, store position-major bf16
#pragma unroll
  for (int qs = 0; qs < 2; ++qs) {
    float inv = 1.f / lrow[qs];
    int q = q0 + w * 32 + qs * 16 + l15;
#pragma unroll
    for (int dt = 0; dt < 8; ++dt) {
      f4 v = o[qs][dt];
      ushort4 st;
      st.x = f2bf(v.x * inv); st.y = f2bf(v.y * inv);
      st.z = f2bf(v.z * inv); st.w = f2bf(v.w * inv);
      *(ushort4*)&Ot[((size_t)b * HW + q) * CCH + h * HD + dt * 16 + quad * 4] = st;
    }
  }
}

extern "C" void kernel_launch(void* const* d_in, const int* in_sizes, int n_in,
                              void* d_out, int out_size, void* d_ws,
                              size_t ws_size, hipStream_t stream) {
  const float* x = (const float*)d_in[0];
  const float* gamma = (const float*)d_in[1];
  const float* beta = (const float*)d_in[2];
  const float* wq = (const float*)d_in[3];
  const float* bq = (const float*)d_in[4];
  const float* wk = (const float*)d_in[5];
  const float* bk = (const float*)d_in[6];
  const float* wv = (const float*)d_in[7];
  const float* bv = (const float*)d_in[8];
  const float* wp = (const float*)d_in[9];
  const float* bp = (const float*)d_in[10];

  const size_t TS = (size_t)BATCH * HW * CCH;  // 8M elements
  unsigned short* wB = (unsigned short*)d_ws;  // 4 x 512x512 bf16
  unsigned short* hn = wB + (size_t)4 * CCH * CCH;
  unsigned short* Qt = hn + TS;
  unsigned short* Kt = Qt + TS;
  unsigned short* Vc = Kt + TS;
  unsigned short* Ot = hn;  // reuse hn after QKV GEMMs

  wcvt_kernel<<<dim3(256, 4), 256, 0, stream>>>(wq, wk, wv, wp, wB);
  gn_kernel<<<dim3(BATCH * 32), 256, 0, stream>>>(x, gamma, beta, hn);
  dim3 gg(4, 8, BATCH);
  gemm_kernel<0><<<gg, 256, 0, stream>>>(hn, wB + 0 * CCH * CCH, bq, nullptr, Qt);
  gemm_kernel<0><<<gg, 256, 0, stream>>>(hn, wB + 1 * CCH * CCH, bk, nullptr, Kt);
  gemm_kernel<1><<<gg, 256, 0, stream>>>(hn, wB + 2 * CCH * CCH, bv, nullptr, Vc);
  attn_kernel<<<dim3(8, NH, BATCH), 256, 0, stream>>>(Qt, Kt, Vc, Ot);
  gemm_kernel<2><<<gg, 256, 0, stream>>>(Ot, wB + 3 * CCH * CCH, bp, x, d_out);
}